// Round 10
// baseline (1968.541 us; speedup 1.0000x reference)
//
#include <hip/hip_runtime.h>

#define B 4
#define N 8192
#define H 256
#define E 8192
#define M 2048
#define T_ITERS 8
#define ET 4

typedef __bf16 bf16x8 __attribute__((ext_vector_type(8)));
typedef float f32x4 __attribute__((ext_vector_type(4)));

__device__ __forceinline__ unsigned short f2bf(float x) {
    unsigned u = __float_as_uint(x);
    u += 0x7fffu + ((u >> 16) & 1u);
    return (unsigned short)(u >> 16);
}
__device__ __forceinline__ unsigned packsplit(float x) {
    unsigned hi = f2bf(x);
    float hif = __uint_as_float(hi << 16);
    unsigned lo = f2bf(x - hif);
    return (hi << 16) | lo;
}
__device__ __forceinline__ float unpacksplit(unsigned p) {
    return __uint_as_float(p & 0xffff0000u) + __uint_as_float(p << 16);
}
__device__ __forceinline__ float fsig(float x) { return 1.0f / (1.0f + __expf(-x)); }
__device__ __forceinline__ float ftanh(float x) {
    float cx = fminf(fmaxf(x, -30.0f), 30.0f);
    float t = __expf(2.0f * cx);
    return (t - 1.0f) / (t + 1.0f);
}

__device__ __forceinline__ void unpack8(uint4 a, uint4 b, bf16x8& hi, bf16x8& lo) {
    union U { unsigned u[4]; bf16x8 v; } uh, ul;
    uh.u[0] = (a.x >> 16) | (a.y & 0xffff0000u);
    uh.u[1] = (a.z >> 16) | (a.w & 0xffff0000u);
    uh.u[2] = (b.x >> 16) | (b.y & 0xffff0000u);
    uh.u[3] = (b.z >> 16) | (b.w & 0xffff0000u);
    ul.u[0] = (a.x & 0xffffu) | (a.y << 16);
    ul.u[1] = (a.z & 0xffffu) | (a.w << 16);
    ul.u[2] = (b.x & 0xffffu) | (b.y << 16);
    ul.u[3] = (b.z & 0xffffu) | (b.w << 16);
    hi = uh.v; lo = ul.v;
}

// fp32 -> split bf16 hi/lo pack (initial embedding)
__global__ __launch_bounds__(256) void pack_kernel(
    const float* __restrict__ src, unsigned* __restrict__ dst)
{
    const int i = blockIdx.x * 256 + threadIdx.x;
    const float4 v = ((const float4*)src)[i];
    uint4 o = { packsplit(v.x), packsplit(v.y), packsplit(v.z), packsplit(v.w) };
    ((uint4*)dst)[i] = o;
}

// msg weights -> fragment-major
__global__ __launch_bounds__(256) void wtrans_msg(
    const float* __restrict__ W_msg, __bf16* __restrict__ Wmt)
{
    const int f = blockIdx.x * 256 + threadIdx.x;  // 0..32767
    const int ln = f & 63;
    const int t = (f >> 6) & 7;
    const int c16 = (f >> 9) & 15;
    const int e = f >> 13;
    const int col = c16 * 16 + (ln & 15);
    const int k = t * 32 + (ln >> 4) * 8;
    const float* src = W_msg + ((size_t)e * H + col) * H + k;
    const float4 a = *(const float4*)src;
    const float4 b = *(const float4*)(src + 4);
    ushort4 o0 = { f2bf(a.x), f2bf(a.y), f2bf(a.z), f2bf(a.w) };
    ushort4 o1 = { f2bf(b.x), f2bf(b.y), f2bf(b.z), f2bf(b.w) };
    *(ushort4*)(Wmt + (size_t)f * 8) = o0;
    *(ushort4*)(Wmt + (size_t)f * 8 + 4) = o1;
}

// gate weights -> fragment-major (g 0..2: W_ih r,z,n; 3..5: W_hh r,z,n)
__global__ __launch_bounds__(256) void wtrans_gate(
    const float* __restrict__ W_ih, const float* __restrict__ W_hh,
    __bf16* __restrict__ Wt)
{
    const int f = blockIdx.x * 256 + threadIdx.x;  // 0..49151
    const int ln = f & 63;
    const int t = (f >> 6) & 7;
    const int c16 = (f >> 9) & 15;
    const int g = f >> 13;
    const int col = c16 * 16 + (ln & 15);
    const int k = t * 32 + (ln >> 4) * 8;
    const float* src = (g < 3) ? (W_ih + ((size_t)g * H + col) * H + k)
                               : (W_hh + ((size_t)(g - 3) * H + col) * H + k);
    const float4 a = *(const float4*)src;
    const float4 b = *(const float4*)(src + 4);
    ushort4 o0 = { f2bf(a.x), f2bf(a.y), f2bf(a.z), f2bf(a.w) };
    ushort4 o1 = { f2bf(b.x), f2bf(b.y), f2bf(b.z), f2bf(b.w) };
    *(ushort4*)(Wt + (size_t)f * 8) = o0;
    *(ushort4*)(Wt + (size_t)f * 8 + 4) = o1;
}

// ---- combined CSR build: one list per (b, node), all 4 edge-types ----
__global__ __launch_bounds__(256) void countk2(
    const int* __restrict__ ed0, const int* __restrict__ ed1,
    const int* __restrict__ ed2, const int* __restrict__ ed3,
    int* __restrict__ csrn)
{
    const int i = blockIdx.x * 256 + threadIdx.x;  // 0..B*ET*E-1
    const int edge = i & (E - 1);
    const int be = i >> 13;
    const int b = be >> 2, e = be & 3;
    const int* ed = (e == 0) ? ed0 : (e == 1) ? ed1 : (e == 2) ? ed2 : ed3;
    const int tgt = ed[((size_t)b * E + edge) * 2 + 1];
    atomicAdd(&csrn[(size_t)b * N + tgt], 1);
}

__global__ __launch_bounds__(256) void scank(int* __restrict__ csr)
{
    int* d = csr + (size_t)blockIdx.x * N;
    const int t = threadIdx.x;
    __shared__ int part[256];
    int loc[32];
    const int base = t * 32;
    int s = 0;
    #pragma unroll
    for (int i = 0; i < 32; ++i) { loc[i] = d[base + i]; s += loc[i]; }
    part[t] = s;
    __syncthreads();
    if (t == 0) { int a = 0; for (int i = 0; i < 256; ++i) { int v = part[i]; part[i] = a; a += v; } }
    __syncthreads();
    int a = part[t];
    #pragma unroll
    for (int i = 0; i < 32; ++i) { d[base + i] = a; a += loc[i]; }
}

__global__ __launch_bounds__(256) void fillk2(
    const int* __restrict__ ed0, const int* __restrict__ ed1,
    const int* __restrict__ ed2, const int* __restrict__ ed3,
    int* __restrict__ csrn, int* __restrict__ eslot)
{
    const int i = blockIdx.x * 256 + threadIdx.x;
    const int edge = i & (E - 1);
    const int be = i >> 13;
    const int b = be >> 2, e = be & 3;
    const int* ed = (e == 0) ? ed0 : (e == 1) ? ed1 : (e == 2) ? ed2 : ed3;
    const int tgt = ed[((size_t)b * E + edge) * 2 + 1];
    const int pos = atomicAdd(&csrn[(size_t)b * N + tgt], 1);
    eslot[i] = pos;
}

// msg GEMM: message row (h[src] @ W_e^T + b_e) -> bf16 into its CSR slot.
__global__ __launch_bounds__(256) void msgk2(
    const unsigned* __restrict__ hp,
    const int* __restrict__ ed0, const int* __restrict__ ed1,
    const int* __restrict__ ed2, const int* __restrict__ ed3,
    const int* __restrict__ eslot,
    const __bf16* __restrict__ Wmt, const float* __restrict__ b_msg,
    unsigned short* __restrict__ medge, const int bc)
{
    __shared__ __bf16 sHi[64 * 256];
    __shared__ __bf16 sLo[64 * 256];
    __shared__ int s_slot[64];
    const int tid = threadIdx.x;
    const int by = blockIdx.y;           // 0..7
    const int bl = by >> 2, e = by & 3;
    const int b = bc * 2 + bl;
    const int* ed = (e == 0) ? ed0 : (e == 1) ? ed1 : (e == 2) ? ed2 : ed3;
    const int row0 = blockIdx.x * 64;

    if (tid < 64) s_slot[tid] = eslot[(size_t)(b * ET + e) * E + row0 + tid];

    #pragma unroll
    for (int half = 0; half < 2; ++half) {
        const int r = half * 32 + (tid >> 3);
        const int k0 = (tid & 7) * 32;
        const int src = ed[((size_t)b * E + row0 + r) * 2];
        const unsigned* hrow = hp + ((size_t)b * N + src) * H + k0;
        #pragma unroll
        for (int c = 0; c < 4; ++c) {
            uint4 ha = *(const uint4*)(hrow + c * 8);
            uint4 hb = *(const uint4*)(hrow + c * 8 + 4);
            bf16x8 hi, lo; unpack8(ha, hb, hi, lo);
            const int sc = ((k0 >> 3) + c) ^ (r & 7);
            *(bf16x8*)(sHi + r * 256 + sc * 8) = hi;
            *(bf16x8*)(sLo + r * 256 + sc * 8) = lo;
        }
    }
    __syncthreads();

    const int wv = tid >> 6, ln = tid & 63, lq = ln >> 4, lm = ln & 15;
    f32x4 zero = {0.f, 0.f, 0.f, 0.f};
    f32x4 acc[4][4];  // [mt][nt]
    #pragma unroll
    for (int mt = 0; mt < 4; ++mt)
        #pragma unroll
        for (int nt = 0; nt < 4; ++nt) acc[mt][nt] = zero;

    const __bf16* wbase = Wmt + ((size_t)((e * 16 + wv * 4) * 8)) * 512 + ln * 8;
    bf16x8 Wc[4], Wn[4];
    #pragma unroll
    for (int nt = 0; nt < 4; ++nt)
        Wc[nt] = *(const bf16x8*)(wbase + (size_t)(nt * 8) * 512);

    #pragma unroll
    for (int ks = 0; ks < 8; ++ks) {
        if (ks < 7) {
            #pragma unroll
            for (int nt = 0; nt < 4; ++nt)
                Wn[nt] = *(const bf16x8*)(wbase + (size_t)(nt * 8 + ks + 1) * 512);
        }
        bf16x8 ahi[4], alo[4];
        #pragma unroll
        for (int mt = 0; mt < 4; ++mt) {
            const int r = mt * 16 + lm;
            const int sc = (ks * 4 + lq) ^ (r & 7);
            ahi[mt] = *(const bf16x8*)(sHi + r * 256 + sc * 8);
            alo[mt] = *(const bf16x8*)(sLo + r * 256 + sc * 8);
        }
        #pragma unroll
        for (int nt = 0; nt < 4; ++nt)
            #pragma unroll
            for (int mt = 0; mt < 4; ++mt) {
                acc[mt][nt] = __builtin_amdgcn_mfma_f32_16x16x32_bf16(ahi[mt], Wc[nt], acc[mt][nt], 0, 0, 0);
                acc[mt][nt] = __builtin_amdgcn_mfma_f32_16x16x32_bf16(alo[mt], Wc[nt], acc[mt][nt], 0, 0, 0);
            }
        #pragma unroll
        for (int nt = 0; nt < 4; ++nt) Wc[nt] = Wn[nt];
    }

    float bias[4];
    #pragma unroll
    for (int nt = 0; nt < 4; ++nt)
        bias[nt] = b_msg[e * H + wv * 64 + nt * 16 + lm];

    unsigned short* mb = medge + (size_t)bl * (ET * E) * H;
    #pragma unroll
    for (int mt = 0; mt < 4; ++mt)
        #pragma unroll
        for (int rr = 0; rr < 4; ++rr) {
            const int slot = s_slot[mt * 16 + lq * 4 + rr];
            #pragma unroll
            for (int nt = 0; nt < 4; ++nt) {
                const int col = wv * 64 + nt * 16 + lm;
                mb[(size_t)slot * H + col] = f2bf(acc[mt][nt][rr] + bias[nt]);
            }
        }
}

// gather: x[node] = sum of CSR-contiguous medge rows; write packed-split u32.
// Thread = (node, 16-elem k-slice). Dense coalesced output; chunk-local rows.
__global__ __launch_bounds__(256) void gatherk(
    const unsigned short* __restrict__ medge, const int* __restrict__ csrn,
    unsigned* __restrict__ xp, const int bc)
{
    const int tid = threadIdx.x;
    const int local = blockIdx.x * 16 + (tid >> 4);  // 0..16383 chunk-local row
    const int k0 = (tid & 15) * 16;
    const int bl = local >> 13;                      // 0/1
    const int b = bc * 2 + bl;
    const int nn = local & (N - 1);

    const int end = csrn[(size_t)b * N + nn];
    const int start = nn ? csrn[(size_t)b * N + nn - 1] : 0;

    float xs[16];
    #pragma unroll
    for (int j = 0; j < 16; ++j) xs[j] = 0.f;
    const unsigned short* mbase = medge + (size_t)bl * (ET * E) * H + k0;
    for (int i = start; i < end; ++i) {
        const unsigned short* mrow = mbase + (size_t)i * H;
        #pragma unroll
        for (int j = 0; j < 16; j += 4) {
            const ushort4 v = *(const ushort4*)(mrow + j);
            xs[j + 0] += __uint_as_float((unsigned)v.x << 16);
            xs[j + 1] += __uint_as_float((unsigned)v.y << 16);
            xs[j + 2] += __uint_as_float((unsigned)v.z << 16);
            xs[j + 3] += __uint_as_float((unsigned)v.w << 16);
        }
    }
    unsigned* xo = xp + (size_t)local * H + k0;
    #pragma unroll
    for (int c = 0; c < 4; ++c) {
        uint4 o = { packsplit(xs[c*4+0]), packsplit(xs[c*4+1]),
                    packsplit(xs[c*4+2]), packsplit(xs[c*4+3]) };
        *(uint4*)(xo + c * 4) = o;
    }
}

// Fused GRU v4: block = 64 rows x 64 cols (512 thr, 8 waves = 2 col-halves x
// 4 row-quarters; wave = 16 rows x 32 cols, acc 48). A planes (xhi/xlo/hhi/
// hlo) staged dense from xp/hp into 128 KB LDS; weights streamed frag-major,
// double-buffered (k-step slice 24 KB -> L1-dedup across row-quarter waves).
// Writes h_new to hnew (medge reuse) -- col-split blocks share input rows.
__global__ __launch_bounds__(512, 2) void gruk(
    const unsigned* __restrict__ xp, const unsigned* __restrict__ hp,
    const __bf16* __restrict__ Wt,
    const float* __restrict__ b_ih, const float* __restrict__ b_hh,
    unsigned* __restrict__ hnew, const int bc)
{
    __shared__ __bf16 sA[4 * 64 * 256];  // 131072 B; plane stride 16384 elems

    const int tid = threadIdx.x;
    const int rb = blockIdx.x >> 2;
    const int cb = blockIdx.x & 3;
    const int lrow0 = rb * 64;                       // chunk-local row base
    const size_t grow0 = (size_t)bc * 2 * N + lrow0; // global row base (hp)

    // ---- dense staging ----
    #pragma unroll
    for (int i = 0; i < 2; ++i) {
        const int r = (tid >> 4) + 32 * i;   // 0..63
        const int k0 = (tid & 15) * 16;
        const unsigned* xr = xp + (size_t)(lrow0 + r) * H + k0;
        const unsigned* hr = hp + (grow0 + r) * H + k0;
        #pragma unroll
        for (int c = 0; c < 2; ++c) {
            uint4 xa = *(const uint4*)(xr + c * 8);
            uint4 xb = *(const uint4*)(xr + c * 8 + 4);
            uint4 ha = *(const uint4*)(hr + c * 8);
            uint4 hb = *(const uint4*)(hr + c * 8 + 4);
            bf16x8 xhi, xlo, hhi, hlo;
            unpack8(xa, xb, xhi, xlo);
            unpack8(ha, hb, hhi, hlo);
            const int sc = ((k0 >> 3) + c) ^ (r & 7);
            __bf16* base = sA + r * 256 + sc * 8;
            *(bf16x8*)(base)          = xhi;
            *(bf16x8*)(base + 16384)  = xlo;
            *(bf16x8*)(base + 32768)  = hhi;
            *(bf16x8*)(base + 49152)  = hlo;
        }
    }
    __syncthreads();

    const int wv = tid >> 6, ln = tid & 63, lq = ln >> 4, lm = ln & 15;
    const int ch = wv & 1, rq = wv >> 1;
    const int c16b = cb * 4 + ch * 2;    // two c16 tiles: c16b, c16b+1

    f32x4 zero = {0.f, 0.f, 0.f, 0.f};
    f32x4 acc[6][2];
    #pragma unroll
    for (int g = 0; g < 6; ++g) { acc[g][0] = zero; acc[g][1] = zero; }

    const __bf16* wb = Wt + ln * 8;
    bf16x8 Wc[6][2], Wn[6][2];
    #pragma unroll
    for (int g = 0; g < 6; ++g)
        #pragma unroll
        for (int nt = 0; nt < 2; ++nt)
            Wc[g][nt] = *(const bf16x8*)(wb + (size_t)((g * 16 + c16b + nt) * 8) * 512);

    #pragma unroll
    for (int ks = 0; ks < 8; ++ks) {
        if (ks < 7) {
            #pragma unroll
            for (int g = 0; g < 6; ++g)
                #pragma unroll
                for (int nt = 0; nt < 2; ++nt)
                    Wn[g][nt] = *(const bf16x8*)(wb + (size_t)((g * 16 + c16b + nt) * 8 + ks + 1) * 512);
        }
        const int r = rq * 16 + lm;
        const int sc = (ks * 4 + lq) ^ (lm & 7);   // r&7 == lm&7
        const __bf16* ab = sA + r * 256 + sc * 8;
        const bf16x8 xhi = *(const bf16x8*)(ab);
        const bf16x8 xlo = *(const bf16x8*)(ab + 16384);
        const bf16x8 hhi = *(const bf16x8*)(ab + 32768);
        const bf16x8 hlo = *(const bf16x8*)(ab + 49152);
        #pragma unroll
        for (int g = 0; g < 6; ++g) {
            const bf16x8 ahi = (g < 3) ? xhi : hhi;
            const bf16x8 alo = (g < 3) ? xlo : hlo;
            #pragma unroll
            for (int nt = 0; nt < 2; ++nt) {
                acc[g][nt] = __builtin_amdgcn_mfma_f32_16x16x32_bf16(ahi, Wc[g][nt], acc[g][nt], 0, 0, 0);
                acc[g][nt] = __builtin_amdgcn_mfma_f32_16x16x32_bf16(alo, Wc[g][nt], acc[g][nt], 0, 0, 0);
            }
        }
        #pragma unroll
        for (int g = 0; g < 6; ++g) { Wc[g][0] = Wn[g][0]; Wc[g][1] = Wn[g][1]; }
    }

    // ---- fused gates; hold reconstructed from LDS h planes ----
    #pragma unroll
    for (int nt = 0; nt < 2; ++nt) {
        const int col = cb * 64 + ch * 32 + nt * 16 + lm;
        const float bi_r = b_ih[col], bi_z = b_ih[H + col], bi_n = b_ih[2 * H + col];
        const float bh_r = b_hh[col], bh_z = b_hh[H + col], bh_n = b_hh[2 * H + col];
        #pragma unroll
        for (int rr = 0; rr < 4; ++rr) {
            const int lrow = rq * 16 + lq * 4 + rr;  // block-local row
            const int swz = (((col >> 3) ^ (lrow & 7)) << 3) + (col & 7);
            const float hold = (float)sA[32768 + lrow * 256 + swz]
                             + (float)sA[49152 + lrow * 256 + swz];
            const float rg = fsig(acc[0][nt][rr] + bi_r + acc[3][nt][rr] + bh_r);
            const float zg = fsig(acc[1][nt][rr] + bi_z + acc[4][nt][rr] + bh_z);
            const float ng = ftanh(acc[2][nt][rr] + bi_n + rg * (acc[5][nt][rr] + bh_n));
            const float o = (1.0f - zg) * ng + zg * hold;
            hnew[(size_t)(lrow0 + lrow) * H + col] = packsplit(o);
        }
    }
}

// copy chunk's h_new back into hp
__global__ __launch_bounds__(256) void copyk(
    const uint4* __restrict__ src, uint4* __restrict__ dst)
{
    const int i = blockIdx.x * 256 + threadIdx.x;
    dst[i] = src[i];
}

__global__ __launch_bounds__(256) void sel_kernel(
    const unsigned* __restrict__ hpack, const int* __restrict__ nao,
    float* __restrict__ out)
{
    const int row = blockIdx.x * 4 + (threadIdx.x >> 6);
    const int lane = threadIdx.x & 63;
    const int b = row >> 11;  // M = 2048
    const int idx = nao[row];
    const uint4 p = ((const uint4*)(hpack + ((size_t)b * N + idx) * H))[lane];
    float4 v = { unpacksplit(p.x), unpacksplit(p.y), unpacksplit(p.z), unpacksplit(p.w) };
    ((float4*)(out + (size_t)row * H))[lane] = v;
}

__global__ __launch_bounds__(256) void gmean_kernel(
    const float* __restrict__ sel, float* __restrict__ gacc)
{
    const int b = blockIdx.x >> 4;
    const int c = blockIdx.x & 15;
    const int j = threadIdx.x;
    float s = 0.0f;
    const float* base = sel + ((size_t)b * M + (size_t)c * 128) * H + j;
    for (int m = 0; m < 128; ++m) s += base[(size_t)m * H];
    atomicAdd(&gacc[b * H + j], s);
}

__global__ __launch_bounds__(256) void final_kernel(
    const float* __restrict__ gacc, float* __restrict__ out)
{
    const int i = blockIdx.x * 256 + threadIdx.x;
    const size_t sel_sz = (size_t)B * M * H;
    if (i < B * M) {
        out[sel_sz + i] = 1.0f;
    } else {
        const int j = i - B * M;
        out[sel_sz + B * M + j] = tanhf(gacc[j] * (1.0f / (float)M));
    }
}

extern "C" void kernel_launch(void* const* d_in, const int* in_sizes, int n_in,
                              void* d_out, int out_size, void* d_ws, size_t ws_size,
                              hipStream_t stream) {
    const float* emb  = (const float*)d_in[0];
    const int*   nao  = (const int*)d_in[2];
    const int*   ed0  = (const int*)d_in[3];
    const int*   ed1  = (const int*)d_in[4];
    const int*   ed2  = (const int*)d_in[5];
    const int*   ed3  = (const int*)d_in[6];
    const float* W_msg = (const float*)d_in[7];
    const float* b_msg = (const float*)d_in[8];
    const float* W_ih  = (const float*)d_in[9];
    const float* W_hh  = (const float*)d_in[10];
    const float* b_ih  = (const float*)d_in[11];
    const float* b_hh  = (const float*)d_in[12];
    float* out = (float*)d_out;

    const size_t helems = (size_t)B * N * H;       // 8.39M
    const size_t chrows = (size_t)2 * N;           // rows per chunk (2 batches)

    // ws layout (~86 MB total)
    unsigned*       hp    = (unsigned*)d_ws;                              // 33.55 MB
    unsigned short* medge = (unsigned short*)(hp + helems);               // 33.55 MB (2 batches; tail reused as hnew)
    unsigned*       xp    = (unsigned*)(medge + (size_t)2 * ET * E * H);  // 16.78 MB (2 batches)
    __bf16*   Wmt   = (__bf16*)(xp + chrows * H);                         // 0.52 MB
    __bf16*   Wt    = Wmt + (size_t)ET * 16 * 8 * 64 * 8;                 // 0.79 MB
    int*      csrn  = (int*)(Wt + (size_t)6 * 16 * 8 * 64 * 8);           // 0.13 MB
    int*      eslot = csrn + (size_t)B * N;                               // 0.52 MB
    float*    gacc  = (float*)(eslot + (size_t)B * ET * E);               // 4 KB

    unsigned* hnew = (unsigned*)medge;   // 16.8 MB, alive only gruk->copyk

    // ---- setup ----
    pack_kernel<<<dim3(helems / 4 / 256), 256, 0, stream>>>(emb, hp);
    wtrans_msg<<<dim3(128), 256, 0, stream>>>(W_msg, Wmt);
    wtrans_gate<<<dim3(192), 256, 0, stream>>>(W_ih, W_hh, Wt);
    hipMemsetAsync(csrn, 0, (size_t)B * N * sizeof(int), stream);
    countk2<<<dim3(B * ET * E / 256), 256, 0, stream>>>(ed0, ed1, ed2, ed3, csrn);
    scank<<<dim3(B), 256, 0, stream>>>(csrn);
    fillk2<<<dim3(B * ET * E / 256), 256, 0, stream>>>(ed0, ed1, ed2, ed3, csrn, eslot);

    // ---- T iterations, 2-batch chunks ----
    for (int t = 0; t < T_ITERS; ++t) {
        for (int bc = 0; bc < 2; ++bc) {
            msgk2<<<dim3(E / 64, 2 * ET), 256, 0, stream>>>(
                hp, ed0, ed1, ed2, ed3, eslot, Wmt, b_msg, medge, bc);
            gatherk<<<dim3(chrows / 16), 256, 0, stream>>>(medge, csrn, xp, bc);
            gruk<<<dim3((chrows / 64) * 4), 512, 0, stream>>>(
                xp, hp, Wt, b_ih, b_hh, hnew, bc);
            copyk<<<dim3(chrows * H / 4 / 256), 256, 0, stream>>>(
                (const uint4*)hnew, (uint4*)(hp + (size_t)bc * chrows * H));
        }
    }

    // ---- epilogue ----
    hipMemsetAsync(gacc, 0, (size_t)B * H * sizeof(float), stream);
    sel_kernel<<<dim3(B * M / 4), 256, 0, stream>>>(hp, nao, out);
    gmean_kernel<<<dim3(B * 16), 256, 0, stream>>>(out, gacc);
    final_kernel<<<dim3((B * M + B * H) / 256), 256, 0, stream>>>(gacc, out);
}

// Round 11
// 1780.007 us; speedup vs baseline: 1.1059x; 1.1059x over previous
//
#include <hip/hip_runtime.h>

#define B 4
#define N 8192
#define H 256
#define E 8192
#define M 2048
#define T_ITERS 8
#define ET 4

typedef __bf16 bf16x8 __attribute__((ext_vector_type(8)));
typedef float f32x4 __attribute__((ext_vector_type(4)));

__device__ __forceinline__ unsigned short f2bf(float x) {
    unsigned u = __float_as_uint(x);
    u += 0x7fffu + ((u >> 16) & 1u);
    return (unsigned short)(u >> 16);
}
__device__ __forceinline__ unsigned packsplit(float x) {
    unsigned hi = f2bf(x);
    float hif = __uint_as_float(hi << 16);
    unsigned lo = f2bf(x - hif);
    return (hi << 16) | lo;
}
__device__ __forceinline__ float unpacksplit(unsigned p) {
    return __uint_as_float(p & 0xffff0000u) + __uint_as_float(p << 16);
}
__device__ __forceinline__ float fsig(float x) { return 1.0f / (1.0f + __expf(-x)); }
__device__ __forceinline__ float ftanh(float x) {
    float cx = fminf(fmaxf(x, -30.0f), 30.0f);
    float t = __expf(2.0f * cx);
    return (t - 1.0f) / (t + 1.0f);
}

__device__ __forceinline__ void unpack8(uint4 a, uint4 b, bf16x8& hi, bf16x8& lo) {
    union U { unsigned u[4]; bf16x8 v; } uh, ul;
    uh.u[0] = (a.x >> 16) | (a.y & 0xffff0000u);
    uh.u[1] = (a.z >> 16) | (a.w & 0xffff0000u);
    uh.u[2] = (b.x >> 16) | (b.y & 0xffff0000u);
    uh.u[3] = (b.z >> 16) | (b.w & 0xffff0000u);
    ul.u[0] = (a.x & 0xffffu) | (a.y << 16);
    ul.u[1] = (a.z & 0xffffu) | (a.w << 16);
    ul.u[2] = (b.x & 0xffffu) | (b.y << 16);
    ul.u[3] = (b.z & 0xffffu) | (b.w << 16);
    hi = uh.v; lo = ul.v;
}

// fp32 -> split bf16 hi/lo pack (initial embedding)
__global__ __launch_bounds__(256) void pack_kernel(
    const float* __restrict__ src, unsigned* __restrict__ dst)
{
    const int i = blockIdx.x * 256 + threadIdx.x;
    const float4 v = ((const float4*)src)[i];
    uint4 o = { packsplit(v.x), packsplit(v.y), packsplit(v.z), packsplit(v.w) };
    ((uint4*)dst)[i] = o;
}

// msg weights -> fragment-major
__global__ __launch_bounds__(256) void wtrans_msg(
    const float* __restrict__ W_msg, __bf16* __restrict__ Wmt)
{
    const int f = blockIdx.x * 256 + threadIdx.x;  // 0..32767
    const int ln = f & 63;
    const int t = (f >> 6) & 7;
    const int c16 = (f >> 9) & 15;
    const int e = f >> 13;
    const int col = c16 * 16 + (ln & 15);
    const int k = t * 32 + (ln >> 4) * 8;
    const float* src = W_msg + ((size_t)e * H + col) * H + k;
    const float4 a = *(const float4*)src;
    const float4 b = *(const float4*)(src + 4);
    ushort4 o0 = { f2bf(a.x), f2bf(a.y), f2bf(a.z), f2bf(a.w) };
    ushort4 o1 = { f2bf(b.x), f2bf(b.y), f2bf(b.z), f2bf(b.w) };
    *(ushort4*)(Wmt + (size_t)f * 8) = o0;
    *(ushort4*)(Wmt + (size_t)f * 8 + 4) = o1;
}

// gate weights -> fragment-major (g 0..2: W_ih r,z,n; 3..5: W_hh r,z,n)
__global__ __launch_bounds__(256) void wtrans_gate(
    const float* __restrict__ W_ih, const float* __restrict__ W_hh,
    __bf16* __restrict__ Wt)
{
    const int f = blockIdx.x * 256 + threadIdx.x;  // 0..49151
    const int ln = f & 63;
    const int t = (f >> 6) & 7;
    const int c16 = (f >> 9) & 15;
    const int g = f >> 13;
    const int col = c16 * 16 + (ln & 15);
    const int k = t * 32 + (ln >> 4) * 8;
    const float* src = (g < 3) ? (W_ih + ((size_t)g * H + col) * H + k)
                               : (W_hh + ((size_t)(g - 3) * H + col) * H + k);
    const float4 a = *(const float4*)src;
    const float4 b = *(const float4*)(src + 4);
    ushort4 o0 = { f2bf(a.x), f2bf(a.y), f2bf(a.z), f2bf(a.w) };
    ushort4 o1 = { f2bf(b.x), f2bf(b.y), f2bf(b.z), f2bf(b.w) };
    *(ushort4*)(Wt + (size_t)f * 8) = o0;
    *(ushort4*)(Wt + (size_t)f * 8 + 4) = o1;
}

// ---- combined CSR build: one list per (b, node), all 4 edge-types ----
__global__ __launch_bounds__(256) void countk2(
    const int* __restrict__ ed0, const int* __restrict__ ed1,
    const int* __restrict__ ed2, const int* __restrict__ ed3,
    int* __restrict__ csrn)
{
    const int i = blockIdx.x * 256 + threadIdx.x;  // 0..B*ET*E-1
    const int edge = i & (E - 1);
    const int be = i >> 13;
    const int b = be >> 2, e = be & 3;
    const int* ed = (e == 0) ? ed0 : (e == 1) ? ed1 : (e == 2) ? ed2 : ed3;
    const int tgt = ed[((size_t)b * E + edge) * 2 + 1];
    atomicAdd(&csrn[(size_t)b * N + tgt], 1);
}

__global__ __launch_bounds__(256) void scank(int* __restrict__ csr)
{
    int* d = csr + (size_t)blockIdx.x * N;
    const int t = threadIdx.x;
    __shared__ int part[256];
    int loc[32];
    const int base = t * 32;
    int s = 0;
    #pragma unroll
    for (int i = 0; i < 32; ++i) { loc[i] = d[base + i]; s += loc[i]; }
    part[t] = s;
    __syncthreads();
    if (t == 0) { int a = 0; for (int i = 0; i < 256; ++i) { int v = part[i]; part[i] = a; a += v; } }
    __syncthreads();
    int a = part[t];
    #pragma unroll
    for (int i = 0; i < 32; ++i) { d[base + i] = a; a += loc[i]; }
}

__global__ __launch_bounds__(256) void fillk2(
    const int* __restrict__ ed0, const int* __restrict__ ed1,
    const int* __restrict__ ed2, const int* __restrict__ ed3,
    int* __restrict__ csrn, int* __restrict__ eslot)
{
    const int i = blockIdx.x * 256 + threadIdx.x;
    const int edge = i & (E - 1);
    const int be = i >> 13;
    const int b = be >> 2, e = be & 3;
    const int* ed = (e == 0) ? ed0 : (e == 1) ? ed1 : (e == 2) ? ed2 : ed3;
    const int tgt = ed[((size_t)b * E + edge) * 2 + 1];
    const int pos = atomicAdd(&csrn[(size_t)b * N + tgt], 1);
    eslot[i] = pos;
}

// msg GEMM: message row (h[src] @ W_e^T + b_e) -> bf16 into its CSR slot.
__global__ __launch_bounds__(256) void msgk2(
    const unsigned* __restrict__ hp,
    const int* __restrict__ ed0, const int* __restrict__ ed1,
    const int* __restrict__ ed2, const int* __restrict__ ed3,
    const int* __restrict__ eslot,
    const __bf16* __restrict__ Wmt, const float* __restrict__ b_msg,
    unsigned short* __restrict__ medge, const int bc)
{
    __shared__ __bf16 sHi[64 * 256];
    __shared__ __bf16 sLo[64 * 256];
    __shared__ int s_slot[64];
    const int tid = threadIdx.x;
    const int by = blockIdx.y;           // 0..7
    const int bl = by >> 2, e = by & 3;
    const int b = bc * 2 + bl;
    const int* ed = (e == 0) ? ed0 : (e == 1) ? ed1 : (e == 2) ? ed2 : ed3;
    const int row0 = blockIdx.x * 64;

    if (tid < 64) s_slot[tid] = eslot[(size_t)(b * ET + e) * E + row0 + tid];

    #pragma unroll
    for (int half = 0; half < 2; ++half) {
        const int r = half * 32 + (tid >> 3);
        const int k0 = (tid & 7) * 32;
        const int src = ed[((size_t)b * E + row0 + r) * 2];
        const unsigned* hrow = hp + ((size_t)b * N + src) * H + k0;
        #pragma unroll
        for (int c = 0; c < 4; ++c) {
            uint4 ha = *(const uint4*)(hrow + c * 8);
            uint4 hb = *(const uint4*)(hrow + c * 8 + 4);
            bf16x8 hi, lo; unpack8(ha, hb, hi, lo);
            const int sc = ((k0 >> 3) + c) ^ (r & 7);
            *(bf16x8*)(sHi + r * 256 + sc * 8) = hi;
            *(bf16x8*)(sLo + r * 256 + sc * 8) = lo;
        }
    }
    __syncthreads();

    const int wv = tid >> 6, ln = tid & 63, lq = ln >> 4, lm = ln & 15;
    f32x4 zero = {0.f, 0.f, 0.f, 0.f};
    f32x4 acc[4][4];  // [mt][nt]
    #pragma unroll
    for (int mt = 0; mt < 4; ++mt)
        #pragma unroll
        for (int nt = 0; nt < 4; ++nt) acc[mt][nt] = zero;

    const __bf16* wbase = Wmt + ((size_t)((e * 16 + wv * 4) * 8)) * 512 + ln * 8;
    bf16x8 Wc[4], Wn[4];
    #pragma unroll
    for (int nt = 0; nt < 4; ++nt)
        Wc[nt] = *(const bf16x8*)(wbase + (size_t)(nt * 8) * 512);

    #pragma unroll
    for (int ks = 0; ks < 8; ++ks) {
        if (ks < 7) {
            #pragma unroll
            for (int nt = 0; nt < 4; ++nt)
                Wn[nt] = *(const bf16x8*)(wbase + (size_t)(nt * 8 + ks + 1) * 512);
        }
        bf16x8 ahi[4], alo[4];
        #pragma unroll
        for (int mt = 0; mt < 4; ++mt) {
            const int r = mt * 16 + lm;
            const int sc = (ks * 4 + lq) ^ (r & 7);
            ahi[mt] = *(const bf16x8*)(sHi + r * 256 + sc * 8);
            alo[mt] = *(const bf16x8*)(sLo + r * 256 + sc * 8);
        }
        #pragma unroll
        for (int nt = 0; nt < 4; ++nt)
            #pragma unroll
            for (int mt = 0; mt < 4; ++mt) {
                acc[mt][nt] = __builtin_amdgcn_mfma_f32_16x16x32_bf16(ahi[mt], Wc[nt], acc[mt][nt], 0, 0, 0);
                acc[mt][nt] = __builtin_amdgcn_mfma_f32_16x16x32_bf16(alo[mt], Wc[nt], acc[mt][nt], 0, 0, 0);
            }
        #pragma unroll
        for (int nt = 0; nt < 4; ++nt) Wc[nt] = Wn[nt];
    }

    float bias[4];
    #pragma unroll
    for (int nt = 0; nt < 4; ++nt)
        bias[nt] = b_msg[e * H + wv * 64 + nt * 16 + lm];

    unsigned short* mb = medge + (size_t)bl * (ET * E) * H;
    #pragma unroll
    for (int mt = 0; mt < 4; ++mt)
        #pragma unroll
        for (int rr = 0; rr < 4; ++rr) {
            const int slot = s_slot[mt * 16 + lq * 4 + rr];
            #pragma unroll
            for (int nt = 0; nt < 4; ++nt) {
                const int col = wv * 64 + nt * 16 + lm;
                mb[(size_t)slot * H + col] = f2bf(acc[mt][nt][rr] + bias[nt]);
            }
        }
}

// gather: x[node] = sum of CSR-contiguous medge rows; write packed-split u32.
__global__ __launch_bounds__(256) void gatherk(
    const unsigned short* __restrict__ medge, const int* __restrict__ csrn,
    unsigned* __restrict__ xp, const int bc)
{
    const int tid = threadIdx.x;
    const int local = blockIdx.x * 16 + (tid >> 4);  // 0..16383 chunk-local row
    const int k0 = (tid & 15) * 16;
    const int bl = local >> 13;                      // 0/1
    const int b = bc * 2 + bl;
    const int nn = local & (N - 1);

    const int end = csrn[(size_t)b * N + nn];
    const int start = nn ? csrn[(size_t)b * N + nn - 1] : 0;

    float xs[16];
    #pragma unroll
    for (int j = 0; j < 16; ++j) xs[j] = 0.f;
    const unsigned short* mbase = medge + (size_t)bl * (ET * E) * H + k0;
    for (int i = start; i < end; ++i) {
        const unsigned short* mrow = mbase + (size_t)i * H;
        #pragma unroll
        for (int j = 0; j < 16; j += 4) {
            const ushort4 v = *(const ushort4*)(mrow + j);
            xs[j + 0] += __uint_as_float((unsigned)v.x << 16);
            xs[j + 1] += __uint_as_float((unsigned)v.y << 16);
            xs[j + 2] += __uint_as_float((unsigned)v.z << 16);
            xs[j + 3] += __uint_as_float((unsigned)v.w << 16);
        }
    }
    unsigned* xo = xp + (size_t)local * H + k0;
    #pragma unroll
    for (int c = 0; c < 4; ++c) {
        uint4 o = { packsplit(xs[c*4+0]), packsplit(xs[c*4+1]),
                    packsplit(xs[c*4+2]), packsplit(xs[c*4+3]) };
        *(uint4*)(xo + c * 4) = o;
    }
}

// Fused GRU v5 (round-6 shape revived): block = 32 rows x 128 cols, 256 thr,
// 4 waves (wave = 32 rows x 32 cols), 64 KB LDS -> 2 blocks/CU. A planes
// staged from packed xp/hp; weights streamed frag-major, double-buffered.
// Writes h_new to hnew (medge alias); copyk moves it back into hp.
__global__ __launch_bounds__(256, 2) void gruk(
    const unsigned* __restrict__ xp, const unsigned* __restrict__ hp,
    const __bf16* __restrict__ Wt,
    const float* __restrict__ b_ih, const float* __restrict__ b_hh,
    unsigned* __restrict__ hnew, const int bc)
{
    __shared__ __bf16 sA[4 * 32 * 256];  // 65536 B; plane stride 8192 elems

    const int tid = threadIdx.x;
    const int cb = blockIdx.x & 1;            // column half
    const int rblk = blockIdx.x >> 1;
    const int lrow0 = rblk * 32;                       // chunk-local row base
    const size_t grow0 = (size_t)bc * 2 * N + lrow0;   // global row base (hp)

    // ---- dense staging: thread -> row tid>>3, 32 k at (tid&7)*32 ----
    {
        const int r = tid >> 3;
        const int k0 = (tid & 7) * 32;
        const unsigned* xr = xp + (size_t)(lrow0 + r) * H + k0;
        const unsigned* hr = hp + (grow0 + r) * H + k0;
        #pragma unroll
        for (int c = 0; c < 4; ++c) {
            uint4 xa = *(const uint4*)(xr + c * 8);
            uint4 xb = *(const uint4*)(xr + c * 8 + 4);
            uint4 ha = *(const uint4*)(hr + c * 8);
            uint4 hb = *(const uint4*)(hr + c * 8 + 4);
            bf16x8 xhi, xlo, hhi, hlo;
            unpack8(xa, xb, xhi, xlo);
            unpack8(ha, hb, hhi, hlo);
            const int sc = ((k0 >> 3) + c) ^ (r & 7);
            __bf16* base = sA + r * 256 + sc * 8;
            *(bf16x8*)(base)          = xhi;
            *(bf16x8*)(base + 8192)   = xlo;
            *(bf16x8*)(base + 16384)  = hhi;
            *(bf16x8*)(base + 24576)  = hlo;
        }
    }
    __syncthreads();

    const int wv = tid >> 6, ln = tid & 63, lq = ln >> 4, lm = ln & 15;
    const int c16a = cb * 8 + wv * 2;   // wave's two c16 tiles

    f32x4 zero = {0.f, 0.f, 0.f, 0.f};
    f32x4 acc[6][2][2];  // [g][nt][mt]
    #pragma unroll
    for (int g = 0; g < 6; ++g)
        #pragma unroll
        for (int nt = 0; nt < 2; ++nt) { acc[g][nt][0] = zero; acc[g][nt][1] = zero; }

    const __bf16* wb = Wt + ln * 8;
    bf16x8 Wc[6][2], Wn[6][2];
    #pragma unroll
    for (int g = 0; g < 6; ++g)
        #pragma unroll
        for (int nt = 0; nt < 2; ++nt)
            Wc[g][nt] = *(const bf16x8*)(wb + (size_t)((g * 16 + c16a + nt) * 8) * 512);

    #pragma unroll
    for (int ks = 0; ks < 8; ++ks) {
        if (ks < 7) {
            #pragma unroll
            for (int g = 0; g < 6; ++g)
                #pragma unroll
                for (int nt = 0; nt < 2; ++nt)
                    Wn[g][nt] = *(const bf16x8*)(wb + (size_t)((g * 16 + c16a + nt) * 8 + ks + 1) * 512);
        }
        // A fragments from LDS: mt -> rows mt*16+lm
        bf16x8 xhi[2], xlo[2], hhi[2], hlo[2];
        #pragma unroll
        for (int mt = 0; mt < 2; ++mt) {
            const int r = mt * 16 + lm;
            const int sc = (ks * 4 + lq) ^ (r & 7);
            const __bf16* ab = sA + r * 256 + sc * 8;
            xhi[mt] = *(const bf16x8*)(ab);
            xlo[mt] = *(const bf16x8*)(ab + 8192);
            hhi[mt] = *(const bf16x8*)(ab + 16384);
            hlo[mt] = *(const bf16x8*)(ab + 24576);
        }
        #pragma unroll
        for (int g = 0; g < 6; ++g) {
            #pragma unroll
            for (int nt = 0; nt < 2; ++nt) {
                #pragma unroll
                for (int mt = 0; mt < 2; ++mt) {
                    const bf16x8 ahi = (g < 3) ? xhi[mt] : hhi[mt];
                    const bf16x8 alo = (g < 3) ? xlo[mt] : hlo[mt];
                    acc[g][nt][mt] = __builtin_amdgcn_mfma_f32_16x16x32_bf16(ahi, Wc[g][nt], acc[g][nt][mt], 0, 0, 0);
                    acc[g][nt][mt] = __builtin_amdgcn_mfma_f32_16x16x32_bf16(alo, Wc[g][nt], acc[g][nt][mt], 0, 0, 0);
                }
            }
        }
        #pragma unroll
        for (int g = 0; g < 6; ++g)
            #pragma unroll
            for (int nt = 0; nt < 2; ++nt) Wc[g][nt] = Wn[g][nt];
    }

    // ---- fused gates; hold reconstructed from LDS h planes ----
    #pragma unroll
    for (int nt = 0; nt < 2; ++nt) {
        const int col = (c16a + nt) * 16 + lm;
        const float bi_r = b_ih[col], bi_z = b_ih[H + col], bi_n = b_ih[2 * H + col];
        const float bh_r = b_hh[col], bh_z = b_hh[H + col], bh_n = b_hh[2 * H + col];
        #pragma unroll
        for (int mt = 0; mt < 2; ++mt) {
            #pragma unroll
            for (int rr = 0; rr < 4; ++rr) {
                const int lrow = mt * 16 + lq * 4 + rr;  // block-local row
                const int swz = (((col >> 3) ^ (lrow & 7)) << 3) + (col & 7);
                const float hold = (float)sA[16384 + lrow * 256 + swz]
                                 + (float)sA[24576 + lrow * 256 + swz];
                const float rg = fsig(acc[0][nt][mt][rr] + bi_r + acc[3][nt][mt][rr] + bh_r);
                const float zg = fsig(acc[1][nt][mt][rr] + bi_z + acc[4][nt][mt][rr] + bh_z);
                const float ng = ftanh(acc[2][nt][mt][rr] + bi_n + rg * (acc[5][nt][mt][rr] + bh_n));
                const float o = (1.0f - zg) * ng + zg * hold;
                hnew[(size_t)(lrow0 + lrow) * H + col] = packsplit(o);
            }
        }
    }
}

// copy chunk's h_new back into hp
__global__ __launch_bounds__(256) void copyk(
    const uint4* __restrict__ src, uint4* __restrict__ dst)
{
    const int i = blockIdx.x * 256 + threadIdx.x;
    dst[i] = src[i];
}

__global__ __launch_bounds__(256) void sel_kernel(
    const unsigned* __restrict__ hpack, const int* __restrict__ nao,
    float* __restrict__ out)
{
    const int row = blockIdx.x * 4 + (threadIdx.x >> 6);
    const int lane = threadIdx.x & 63;
    const int b = row >> 11;  // M = 2048
    const int idx = nao[row];
    const uint4 p = ((const uint4*)(hpack + ((size_t)b * N + idx) * H))[lane];
    float4 v = { unpacksplit(p.x), unpacksplit(p.y), unpacksplit(p.z), unpacksplit(p.w) };
    ((float4*)(out + (size_t)row * H))[lane] = v;
}

__global__ __launch_bounds__(256) void gmean_kernel(
    const float* __restrict__ sel, float* __restrict__ gacc)
{
    const int b = blockIdx.x >> 4;
    const int c = blockIdx.x & 15;
    const int j = threadIdx.x;
    float s = 0.0f;
    const float* base = sel + ((size_t)b * M + (size_t)c * 128) * H + j;
    for (int m = 0; m < 128; ++m) s += base[(size_t)m * H];
    atomicAdd(&gacc[b * H + j], s);
}

__global__ __launch_bounds__(256) void final_kernel(
    const float* __restrict__ gacc, float* __restrict__ out)
{
    const int i = blockIdx.x * 256 + threadIdx.x;
    const size_t sel_sz = (size_t)B * M * H;
    if (i < B * M) {
        out[sel_sz + i] = 1.0f;
    } else {
        const int j = i - B * M;
        out[sel_sz + B * M + j] = tanhf(gacc[j] * (1.0f / (float)M));
    }
}

extern "C" void kernel_launch(void* const* d_in, const int* in_sizes, int n_in,
                              void* d_out, int out_size, void* d_ws, size_t ws_size,
                              hipStream_t stream) {
    const float* emb  = (const float*)d_in[0];
    const int*   nao  = (const int*)d_in[2];
    const int*   ed0  = (const int*)d_in[3];
    const int*   ed1  = (const int*)d_in[4];
    const int*   ed2  = (const int*)d_in[5];
    const int*   ed3  = (const int*)d_in[6];
    const float* W_msg = (const float*)d_in[7];
    const float* b_msg = (const float*)d_in[8];
    const float* W_ih  = (const float*)d_in[9];
    const float* W_hh  = (const float*)d_in[10];
    const float* b_ih  = (const float*)d_in[11];
    const float* b_hh  = (const float*)d_in[12];
    float* out = (float*)d_out;

    const size_t helems = (size_t)B * N * H;       // 8.39M
    const size_t chrows = (size_t)2 * N;           // rows per chunk (2 batches)

    // ws layout (~86 MB total)
    unsigned*       hp    = (unsigned*)d_ws;                              // 33.55 MB
    unsigned short* medge = (unsigned short*)(hp + helems);               // 33.55 MB (2 batches; reused as hnew)
    unsigned*       xp    = (unsigned*)(medge + (size_t)2 * ET * E * H);  // 16.78 MB (chunk)
    __bf16*   Wmt   = (__bf16*)(xp + chrows * H);                         // 0.52 MB
    __bf16*   Wt    = Wmt + (size_t)ET * 16 * 8 * 64 * 8;                 // 0.79 MB
    int*      csrn  = (int*)(Wt + (size_t)6 * 16 * 8 * 64 * 8);           // 0.13 MB
    int*      eslot = csrn + (size_t)B * N;                               // 0.52 MB
    float*    gacc  = (float*)(eslot + (size_t)B * ET * E);               // 4 KB

    unsigned* hnew = (unsigned*)medge;   // 16.8 MB, alive only gruk->copyk

    // ---- setup ----
    pack_kernel<<<dim3(helems / 4 / 256), 256, 0, stream>>>(emb, hp);
    wtrans_msg<<<dim3(128), 256, 0, stream>>>(W_msg, Wmt);
    wtrans_gate<<<dim3(192), 256, 0, stream>>>(W_ih, W_hh, Wt);
    hipMemsetAsync(csrn, 0, (size_t)B * N * sizeof(int), stream);
    countk2<<<dim3(B * ET * E / 256), 256, 0, stream>>>(ed0, ed1, ed2, ed3, csrn);
    scank<<<dim3(B), 256, 0, stream>>>(csrn);
    fillk2<<<dim3(B * ET * E / 256), 256, 0, stream>>>(ed0, ed1, ed2, ed3, csrn, eslot);

    // ---- T iterations, 2-batch chunks ----
    for (int t = 0; t < T_ITERS; ++t) {
        for (int bc = 0; bc < 2; ++bc) {
            msgk2<<<dim3(E / 64, 2 * ET), 256, 0, stream>>>(
                hp, ed0, ed1, ed2, ed3, eslot, Wmt, b_msg, medge, bc);
            gatherk<<<dim3(chrows / 16), 256, 0, stream>>>(medge, csrn, xp, bc);
            gruk<<<dim3((chrows / 32) * 2), 256, 0, stream>>>(
                xp, hp, Wt, b_ih, b_hh, hnew, bc);
            copyk<<<dim3(chrows * H / 4 / 256), 256, 0, stream>>>(
                (const uint4*)hnew, (uint4*)(hp + (size_t)bc * chrows * H));
        }
    }

    // ---- epilogue ----
    hipMemsetAsync(gacc, 0, (size_t)B * H * sizeof(float), stream);
    sel_kernel<<<dim3(B * M / 4), 256, 0, stream>>>(hp, nao, out);
    gmean_kernel<<<dim3(B * 16), 256, 0, stream>>>(out, gacc);
    final_kernel<<<dim3((B * M + B * H) / 256), 256, 0, stream>>>(gacc, out);
}

// Round 12
// 1602.328 us; speedup vs baseline: 1.2286x; 1.1109x over previous
//
#include <hip/hip_runtime.h>

#define B 4
#define N 8192
#define H 256
#define E 8192
#define M 2048
#define T_ITERS 8
#define ET 4

typedef __bf16 bf16x8 __attribute__((ext_vector_type(8)));
typedef float f32x4 __attribute__((ext_vector_type(4)));

__device__ __forceinline__ unsigned short f2bf(float x) {
    unsigned u = __float_as_uint(x);
    u += 0x7fffu + ((u >> 16) & 1u);
    return (unsigned short)(u >> 16);
}
__device__ __forceinline__ unsigned packsplit(float x) {
    unsigned hi = f2bf(x);
    float hif = __uint_as_float(hi << 16);
    unsigned lo = f2bf(x - hif);
    return (hi << 16) | lo;
}
__device__ __forceinline__ float unpacksplit(unsigned p) {
    return __uint_as_float(p & 0xffff0000u) + __uint_as_float(p << 16);
}
__device__ __forceinline__ float fsig(float x) { return 1.0f / (1.0f + __expf(-x)); }
__device__ __forceinline__ float ftanh(float x) {
    float cx = fminf(fmaxf(x, -30.0f), 30.0f);
    float t = __expf(2.0f * cx);
    return (t - 1.0f) / (t + 1.0f);
}

__device__ __forceinline__ void unpack8(uint4 a, uint4 b, bf16x8& hi, bf16x8& lo) {
    union U { unsigned u[4]; bf16x8 v; } uh, ul;
    uh.u[0] = (a.x >> 16) | (a.y & 0xffff0000u);
    uh.u[1] = (a.z >> 16) | (a.w & 0xffff0000u);
    uh.u[2] = (b.x >> 16) | (b.y & 0xffff0000u);
    uh.u[3] = (b.z >> 16) | (b.w & 0xffff0000u);
    ul.u[0] = (a.x & 0xffffu) | (a.y << 16);
    ul.u[1] = (a.z & 0xffffu) | (a.w << 16);
    ul.u[2] = (b.x & 0xffffu) | (b.y << 16);
    ul.u[3] = (b.z & 0xffffu) | (b.w << 16);
    hi = uh.v; lo = ul.v;
}

// fp32 -> split bf16 hi/lo pack (initial embedding)
__global__ __launch_bounds__(256) void pack_kernel(
    const float* __restrict__ src, unsigned* __restrict__ dst)
{
    const int i = blockIdx.x * 256 + threadIdx.x;
    const float4 v = ((const float4*)src)[i];
    uint4 o = { packsplit(v.x), packsplit(v.y), packsplit(v.z), packsplit(v.w) };
    ((uint4*)dst)[i] = o;
}

// msg weights -> fragment-major
__global__ __launch_bounds__(256) void wtrans_msg(
    const float* __restrict__ W_msg, __bf16* __restrict__ Wmt)
{
    const int f = blockIdx.x * 256 + threadIdx.x;  // 0..32767
    const int ln = f & 63;
    const int t = (f >> 6) & 7;
    const int c16 = (f >> 9) & 15;
    const int e = f >> 13;
    const int col = c16 * 16 + (ln & 15);
    const int k = t * 32 + (ln >> 4) * 8;
    const float* src = W_msg + ((size_t)e * H + col) * H + k;
    const float4 a = *(const float4*)src;
    const float4 b = *(const float4*)(src + 4);
    ushort4 o0 = { f2bf(a.x), f2bf(a.y), f2bf(a.z), f2bf(a.w) };
    ushort4 o1 = { f2bf(b.x), f2bf(b.y), f2bf(b.z), f2bf(b.w) };
    *(ushort4*)(Wmt + (size_t)f * 8) = o0;
    *(ushort4*)(Wmt + (size_t)f * 8 + 4) = o1;
}

// gate weights -> fragment-major (g 0..2: W_ih r,z,n; 3..5: W_hh r,z,n)
__global__ __launch_bounds__(256) void wtrans_gate(
    const float* __restrict__ W_ih, const float* __restrict__ W_hh,
    __bf16* __restrict__ Wt)
{
    const int f = blockIdx.x * 256 + threadIdx.x;  // 0..49151
    const int ln = f & 63;
    const int t = (f >> 6) & 7;
    const int c16 = (f >> 9) & 15;
    const int g = f >> 13;
    const int col = c16 * 16 + (ln & 15);
    const int k = t * 32 + (ln >> 4) * 8;
    const float* src = (g < 3) ? (W_ih + ((size_t)g * H + col) * H + k)
                               : (W_hh + ((size_t)(g - 3) * H + col) * H + k);
    const float4 a = *(const float4*)src;
    const float4 b = *(const float4*)(src + 4);
    ushort4 o0 = { f2bf(a.x), f2bf(a.y), f2bf(a.z), f2bf(a.w) };
    ushort4 o1 = { f2bf(b.x), f2bf(b.y), f2bf(b.z), f2bf(b.w) };
    *(ushort4*)(Wt + (size_t)f * 8) = o0;
    *(ushort4*)(Wt + (size_t)f * 8 + 4) = o1;
}

// ---- combined CSR build: one list per (b, node), all 4 edge-types ----
__global__ __launch_bounds__(256) void countk2(
    const int* __restrict__ ed0, const int* __restrict__ ed1,
    const int* __restrict__ ed2, const int* __restrict__ ed3,
    int* __restrict__ csrn)
{
    const int i = blockIdx.x * 256 + threadIdx.x;  // 0..B*ET*E-1
    const int edge = i & (E - 1);
    const int be = i >> 13;
    const int b = be >> 2, e = be & 3;
    const int* ed = (e == 0) ? ed0 : (e == 1) ? ed1 : (e == 2) ? ed2 : ed3;
    const int tgt = ed[((size_t)b * E + edge) * 2 + 1];
    atomicAdd(&csrn[(size_t)b * N + tgt], 1);
}

__global__ __launch_bounds__(256) void scank(int* __restrict__ csr)
{
    int* d = csr + (size_t)blockIdx.x * N;
    const int t = threadIdx.x;
    __shared__ int part[256];
    int loc[32];
    const int base = t * 32;
    int s = 0;
    #pragma unroll
    for (int i = 0; i < 32; ++i) { loc[i] = d[base + i]; s += loc[i]; }
    part[t] = s;
    __syncthreads();
    if (t == 0) { int a = 0; for (int i = 0; i < 256; ++i) { int v = part[i]; part[i] = a; a += v; } }
    __syncthreads();
    int a = part[t];
    #pragma unroll
    for (int i = 0; i < 32; ++i) { d[base + i] = a; a += loc[i]; }
}

__global__ __launch_bounds__(256) void fillk2(
    const int* __restrict__ ed0, const int* __restrict__ ed1,
    const int* __restrict__ ed2, const int* __restrict__ ed3,
    int* __restrict__ csrn, int* __restrict__ eslot)
{
    const int i = blockIdx.x * 256 + threadIdx.x;
    const int edge = i & (E - 1);
    const int be = i >> 13;
    const int b = be >> 2, e = be & 3;
    const int* ed = (e == 0) ? ed0 : (e == 1) ? ed1 : (e == 2) ? ed2 : ed3;
    const int tgt = ed[((size_t)b * E + edge) * 2 + 1];
    const int pos = atomicAdd(&csrn[(size_t)b * N + tgt], 1);
    eslot[i] = pos;
}

// msg GEMM: message row (h[src] @ W_e^T + b_e) -> bf16 into its CSR slot.
__global__ __launch_bounds__(256) void msgk2(
    const unsigned* __restrict__ hp,
    const int* __restrict__ ed0, const int* __restrict__ ed1,
    const int* __restrict__ ed2, const int* __restrict__ ed3,
    const int* __restrict__ eslot,
    const __bf16* __restrict__ Wmt, const float* __restrict__ b_msg,
    unsigned short* __restrict__ medge, const int bc)
{
    __shared__ __bf16 sHi[64 * 256];
    __shared__ __bf16 sLo[64 * 256];
    __shared__ int s_slot[64];
    const int tid = threadIdx.x;
    const int by = blockIdx.y;           // 0..7
    const int bl = by >> 2, e = by & 3;
    const int b = bc * 2 + bl;
    const int* ed = (e == 0) ? ed0 : (e == 1) ? ed1 : (e == 2) ? ed2 : ed3;
    const int row0 = blockIdx.x * 64;

    if (tid < 64) s_slot[tid] = eslot[(size_t)(b * ET + e) * E + row0 + tid];

    #pragma unroll
    for (int half = 0; half < 2; ++half) {
        const int r = half * 32 + (tid >> 3);
        const int k0 = (tid & 7) * 32;
        const int src = ed[((size_t)b * E + row0 + r) * 2];
        const unsigned* hrow = hp + ((size_t)b * N + src) * H + k0;
        #pragma unroll
        for (int c = 0; c < 4; ++c) {
            uint4 ha = *(const uint4*)(hrow + c * 8);
            uint4 hb = *(const uint4*)(hrow + c * 8 + 4);
            bf16x8 hi, lo; unpack8(ha, hb, hi, lo);
            const int sc = ((k0 >> 3) + c) ^ (r & 7);
            *(bf16x8*)(sHi + r * 256 + sc * 8) = hi;
            *(bf16x8*)(sLo + r * 256 + sc * 8) = lo;
        }
    }
    __syncthreads();

    const int wv = tid >> 6, ln = tid & 63, lq = ln >> 4, lm = ln & 15;
    f32x4 zero = {0.f, 0.f, 0.f, 0.f};
    f32x4 acc[4][4];  // [mt][nt]
    #pragma unroll
    for (int mt = 0; mt < 4; ++mt)
        #pragma unroll
        for (int nt = 0; nt < 4; ++nt) acc[mt][nt] = zero;

    const __bf16* wbase = Wmt + ((size_t)((e * 16 + wv * 4) * 8)) * 512 + ln * 8;
    bf16x8 Wc[4], Wn[4];
    #pragma unroll
    for (int nt = 0; nt < 4; ++nt)
        Wc[nt] = *(const bf16x8*)(wbase + (size_t)(nt * 8) * 512);

    #pragma unroll
    for (int ks = 0; ks < 8; ++ks) {
        if (ks < 7) {
            #pragma unroll
            for (int nt = 0; nt < 4; ++nt)
                Wn[nt] = *(const bf16x8*)(wbase + (size_t)(nt * 8 + ks + 1) * 512);
        }
        bf16x8 ahi[4], alo[4];
        #pragma unroll
        for (int mt = 0; mt < 4; ++mt) {
            const int r = mt * 16 + lm;
            const int sc = (ks * 4 + lq) ^ (r & 7);
            ahi[mt] = *(const bf16x8*)(sHi + r * 256 + sc * 8);
            alo[mt] = *(const bf16x8*)(sLo + r * 256 + sc * 8);
        }
        #pragma unroll
        for (int nt = 0; nt < 4; ++nt)
            #pragma unroll
            for (int mt = 0; mt < 4; ++mt) {
                acc[mt][nt] = __builtin_amdgcn_mfma_f32_16x16x32_bf16(ahi[mt], Wc[nt], acc[mt][nt], 0, 0, 0);
                acc[mt][nt] = __builtin_amdgcn_mfma_f32_16x16x32_bf16(alo[mt], Wc[nt], acc[mt][nt], 0, 0, 0);
            }
        #pragma unroll
        for (int nt = 0; nt < 4; ++nt) Wc[nt] = Wn[nt];
    }

    float bias[4];
    #pragma unroll
    for (int nt = 0; nt < 4; ++nt)
        bias[nt] = b_msg[e * H + wv * 64 + nt * 16 + lm];

    unsigned short* mb = medge + (size_t)bl * (ET * E) * H;
    #pragma unroll
    for (int mt = 0; mt < 4; ++mt)
        #pragma unroll
        for (int rr = 0; rr < 4; ++rr) {
            const int slot = s_slot[mt * 16 + lq * 4 + rr];
            #pragma unroll
            for (int nt = 0; nt < 4; ++nt) {
                const int col = wv * 64 + nt * 16 + lm;
                mb[(size_t)slot * H + col] = f2bf(acc[mt][nt][rr] + bias[nt]);
            }
        }
}

// gather: x[node] = sum of CSR-contiguous medge rows; write packed-split u32.
__global__ __launch_bounds__(256) void gatherk(
    const unsigned short* __restrict__ medge, const int* __restrict__ csrn,
    unsigned* __restrict__ xp, const int bc)
{
    const int tid = threadIdx.x;
    const int local = blockIdx.x * 16 + (tid >> 4);  // 0..16383 chunk-local row
    const int k0 = (tid & 15) * 16;
    const int bl = local >> 13;                      // 0/1
    const int b = bc * 2 + bl;
    const int nn = local & (N - 1);

    const int end = csrn[(size_t)b * N + nn];
    const int start = nn ? csrn[(size_t)b * N + nn - 1] : 0;

    float xs[16];
    #pragma unroll
    for (int j = 0; j < 16; ++j) xs[j] = 0.f;
    const unsigned short* mbase = medge + (size_t)bl * (ET * E) * H + k0;
    for (int i = start; i < end; ++i) {
        const unsigned short* mrow = mbase + (size_t)i * H;
        #pragma unroll
        for (int j = 0; j < 16; j += 4) {
            const ushort4 v = *(const ushort4*)(mrow + j);
            xs[j + 0] += __uint_as_float((unsigned)v.x << 16);
            xs[j + 1] += __uint_as_float((unsigned)v.y << 16);
            xs[j + 2] += __uint_as_float((unsigned)v.z << 16);
            xs[j + 3] += __uint_as_float((unsigned)v.w << 16);
        }
    }
    unsigned* xo = xp + (size_t)local * H + k0;
    #pragma unroll
    for (int c = 0; c < 4; ++c) {
        uint4 o = { packsplit(xs[c*4+0]), packsplit(xs[c*4+1]),
                    packsplit(xs[c*4+2]), packsplit(xs[c*4+3]) };
        *(uint4*)(xo + c * 4) = o;
    }
}

// Fused GRU v6: block = 32 rows x ALL 256 cols, 512 thr (8 waves; wave =
// 32 rows x 32 cols, acc 96 VGPR). A fetched ONCE per row (no col-split dup),
// 64 KB LDS -> 2 blocks/CU = 16 waves/CU. Blocks own rows exclusively ->
// in-place hp update (no hnew, no copyk). Weights frag-major, double-buffered.
__global__ __launch_bounds__(512, 2) void gruk(
    const unsigned* __restrict__ xp, unsigned* __restrict__ hp,
    const __bf16* __restrict__ Wt,
    const float* __restrict__ b_ih, const float* __restrict__ b_hh,
    const int bc)
{
    __shared__ __bf16 sA[4 * 32 * 256];  // 65536 B; plane stride 8192 elems

    const int tid = threadIdx.x;
    const int lrow0 = blockIdx.x * 32;                 // chunk-local row base
    const size_t grow0 = (size_t)bc * 2 * N + lrow0;   // global row base (hp)

    // ---- dense staging: thread -> row tid>>4, 16 k at (tid&15)*16 ----
    {
        const int r = tid >> 4;
        const int k0 = (tid & 15) * 16;
        const unsigned* xr = xp + (size_t)(lrow0 + r) * H + k0;
        const unsigned* hr = hp + (grow0 + r) * H + k0;
        #pragma unroll
        for (int c = 0; c < 2; ++c) {
            uint4 xa = *(const uint4*)(xr + c * 8);
            uint4 xb = *(const uint4*)(xr + c * 8 + 4);
            uint4 ha = *(const uint4*)(hr + c * 8);
            uint4 hb = *(const uint4*)(hr + c * 8 + 4);
            bf16x8 xhi, xlo, hhi, hlo;
            unpack8(xa, xb, xhi, xlo);
            unpack8(ha, hb, hhi, hlo);
            const int sc = ((k0 >> 3) + c) ^ (r & 7);
            __bf16* base = sA + r * 256 + sc * 8;
            *(bf16x8*)(base)          = xhi;
            *(bf16x8*)(base + 8192)   = xlo;
            *(bf16x8*)(base + 16384)  = hhi;
            *(bf16x8*)(base + 24576)  = hlo;
        }
    }
    __syncthreads();

    const int wv = tid >> 6, ln = tid & 63, lq = ln >> 4, lm = ln & 15;
    const int c16a = wv * 2;   // wave's two c16 tiles: cols [wv*32, wv*32+32)

    f32x4 zero = {0.f, 0.f, 0.f, 0.f};
    f32x4 acc[6][2][2];  // [g][nt][mt]
    #pragma unroll
    for (int g = 0; g < 6; ++g)
        #pragma unroll
        for (int nt = 0; nt < 2; ++nt) { acc[g][nt][0] = zero; acc[g][nt][1] = zero; }

    const __bf16* wb = Wt + ln * 8;
    bf16x8 Wc[6][2], Wn[6][2];
    #pragma unroll
    for (int g = 0; g < 6; ++g)
        #pragma unroll
        for (int nt = 0; nt < 2; ++nt)
            Wc[g][nt] = *(const bf16x8*)(wb + (size_t)((g * 16 + c16a + nt) * 8) * 512);

    #pragma unroll
    for (int ks = 0; ks < 8; ++ks) {
        if (ks < 7) {
            #pragma unroll
            for (int g = 0; g < 6; ++g)
                #pragma unroll
                for (int nt = 0; nt < 2; ++nt)
                    Wn[g][nt] = *(const bf16x8*)(wb + (size_t)((g * 16 + c16a + nt) * 8 + ks + 1) * 512);
        }
        // A fragments from LDS: mt -> rows mt*16+lm
        bf16x8 xhi[2], xlo[2], hhi[2], hlo[2];
        #pragma unroll
        for (int mt = 0; mt < 2; ++mt) {
            const int r = mt * 16 + lm;
            const int sc = (ks * 4 + lq) ^ (r & 7);
            const __bf16* ab = sA + r * 256 + sc * 8;
            xhi[mt] = *(const bf16x8*)(ab);
            xlo[mt] = *(const bf16x8*)(ab + 8192);
            hhi[mt] = *(const bf16x8*)(ab + 16384);
            hlo[mt] = *(const bf16x8*)(ab + 24576);
        }
        #pragma unroll
        for (int g = 0; g < 6; ++g) {
            #pragma unroll
            for (int nt = 0; nt < 2; ++nt) {
                #pragma unroll
                for (int mt = 0; mt < 2; ++mt) {
                    const bf16x8 ahi = (g < 3) ? xhi[mt] : hhi[mt];
                    const bf16x8 alo = (g < 3) ? xlo[mt] : hlo[mt];
                    acc[g][nt][mt] = __builtin_amdgcn_mfma_f32_16x16x32_bf16(ahi, Wc[g][nt], acc[g][nt][mt], 0, 0, 0);
                    acc[g][nt][mt] = __builtin_amdgcn_mfma_f32_16x16x32_bf16(alo, Wc[g][nt], acc[g][nt][mt], 0, 0, 0);
                }
            }
        }
        #pragma unroll
        for (int g = 0; g < 6; ++g)
            #pragma unroll
            for (int nt = 0; nt < 2; ++nt) Wc[g][nt] = Wn[g][nt];
    }

    // ---- fused gates; hold from LDS h planes; in-place hp store ----
    #pragma unroll
    for (int nt = 0; nt < 2; ++nt) {
        const int col = (c16a + nt) * 16 + lm;
        const float bi_r = b_ih[col], bi_z = b_ih[H + col], bi_n = b_ih[2 * H + col];
        const float bh_r = b_hh[col], bh_z = b_hh[H + col], bh_n = b_hh[2 * H + col];
        #pragma unroll
        for (int mt = 0; mt < 2; ++mt) {
            #pragma unroll
            for (int rr = 0; rr < 4; ++rr) {
                const int lrow = mt * 16 + lq * 4 + rr;  // block-local row
                const int swz = (((col >> 3) ^ (lrow & 7)) << 3) + (col & 7);
                const float hold = (float)sA[16384 + lrow * 256 + swz]
                                 + (float)sA[24576 + lrow * 256 + swz];
                const float rg = fsig(acc[0][nt][mt][rr] + bi_r + acc[3][nt][mt][rr] + bh_r);
                const float zg = fsig(acc[1][nt][mt][rr] + bi_z + acc[4][nt][mt][rr] + bh_z);
                const float ng = ftanh(acc[2][nt][mt][rr] + bi_n + rg * (acc[5][nt][mt][rr] + bh_n));
                const float o = (1.0f - zg) * ng + zg * hold;
                hp[(grow0 + lrow) * H + col] = packsplit(o);
            }
        }
    }
}

__global__ __launch_bounds__(256) void sel_kernel(
    const unsigned* __restrict__ hpack, const int* __restrict__ nao,
    float* __restrict__ out)
{
    const int row = blockIdx.x * 4 + (threadIdx.x >> 6);
    const int lane = threadIdx.x & 63;
    const int b = row >> 11;  // M = 2048
    const int idx = nao[row];
    const uint4 p = ((const uint4*)(hpack + ((size_t)b * N + idx) * H))[lane];
    float4 v = { unpacksplit(p.x), unpacksplit(p.y), unpacksplit(p.z), unpacksplit(p.w) };
    ((float4*)(out + (size_t)row * H))[lane] = v;
}

__global__ __launch_bounds__(256) void gmean_kernel(
    const float* __restrict__ sel, float* __restrict__ gacc)
{
    const int b = blockIdx.x >> 4;
    const int c = blockIdx.x & 15;
    const int j = threadIdx.x;
    float s = 0.0f;
    const float* base = sel + ((size_t)b * M + (size_t)c * 128) * H + j;
    for (int m = 0; m < 128; ++m) s += base[(size_t)m * H];
    atomicAdd(&gacc[b * H + j], s);
}

__global__ __launch_bounds__(256) void final_kernel(
    const float* __restrict__ gacc, float* __restrict__ out)
{
    const int i = blockIdx.x * 256 + threadIdx.x;
    const size_t sel_sz = (size_t)B * M * H;
    if (i < B * M) {
        out[sel_sz + i] = 1.0f;
    } else {
        const int j = i - B * M;
        out[sel_sz + B * M + j] = tanhf(gacc[j] * (1.0f / (float)M));
    }
}

extern "C" void kernel_launch(void* const* d_in, const int* in_sizes, int n_in,
                              void* d_out, int out_size, void* d_ws, size_t ws_size,
                              hipStream_t stream) {
    const float* emb  = (const float*)d_in[0];
    const int*   nao  = (const int*)d_in[2];
    const int*   ed0  = (const int*)d_in[3];
    const int*   ed1  = (const int*)d_in[4];
    const int*   ed2  = (const int*)d_in[5];
    const int*   ed3  = (const int*)d_in[6];
    const float* W_msg = (const float*)d_in[7];
    const float* b_msg = (const float*)d_in[8];
    const float* W_ih  = (const float*)d_in[9];
    const float* W_hh  = (const float*)d_in[10];
    const float* b_ih  = (const float*)d_in[11];
    const float* b_hh  = (const float*)d_in[12];
    float* out = (float*)d_out;

    const size_t helems = (size_t)B * N * H;       // 8.39M
    const size_t chrows = (size_t)2 * N;           // rows per chunk (2 batches)

    // ws layout (~86 MB total)
    unsigned*       hp    = (unsigned*)d_ws;                              // 33.55 MB
    unsigned short* medge = (unsigned short*)(hp + helems);               // 33.55 MB (chunk)
    unsigned*       xp    = (unsigned*)(medge + (size_t)2 * ET * E * H);  // 16.78 MB (chunk)
    __bf16*   Wmt   = (__bf16*)(xp + chrows * H);                         // 0.52 MB
    __bf16*   Wt    = Wmt + (size_t)ET * 16 * 8 * 64 * 8;                 // 0.79 MB
    int*      csrn  = (int*)(Wt + (size_t)6 * 16 * 8 * 64 * 8);           // 0.13 MB
    int*      eslot = csrn + (size_t)B * N;                               // 0.52 MB
    float*    gacc  = (float*)(eslot + (size_t)B * ET * E);               // 4 KB

    // ---- setup ----
    pack_kernel<<<dim3(helems / 4 / 256), 256, 0, stream>>>(emb, hp);
    wtrans_msg<<<dim3(128), 256, 0, stream>>>(W_msg, Wmt);
    wtrans_gate<<<dim3(192), 256, 0, stream>>>(W_ih, W_hh, Wt);
    hipMemsetAsync(csrn, 0, (size_t)B * N * sizeof(int), stream);
    countk2<<<dim3(B * ET * E / 256), 256, 0, stream>>>(ed0, ed1, ed2, ed3, csrn);
    scank<<<dim3(B), 256, 0, stream>>>(csrn);
    fillk2<<<dim3(B * ET * E / 256), 256, 0, stream>>>(ed0, ed1, ed2, ed3, csrn, eslot);

    // ---- T iterations, 2-batch chunks ----
    for (int t = 0; t < T_ITERS; ++t) {
        for (int bc = 0; bc < 2; ++bc) {
            msgk2<<<dim3(E / 64, 2 * ET), 256, 0, stream>>>(
                hp, ed0, ed1, ed2, ed3, eslot, Wmt, b_msg, medge, bc);
            gatherk<<<dim3(chrows / 16), 256, 0, stream>>>(medge, csrn, xp, bc);
            gruk<<<dim3(chrows / 32), 512, 0, stream>>>(
                xp, hp, Wt, b_ih, b_hh, bc);
        }
    }

    // ---- epilogue ----
    hipMemsetAsync(gacc, 0, (size_t)B * H * sizeof(float), stream);
    sel_kernel<<<dim3(B * M / 4), 256, 0, stream>>>(hp, nao, out);
    gmean_kernel<<<dim3(B * 16), 256, 0, stream>>>(out, gacc);
    final_kernel<<<dim3((B * M + B * H) / 256), 256, 0, stream>>>(gacc, out);
}